// Round 2
// baseline (206.602 us; speedup 1.0000x reference)
//
#include <hip/hip_runtime.h>

#define CQ 32
#define KQ 128
#define NPTS 384
#define OUTN 1024
#define BQ 8
#define NACC (BQ * OUTN)   // 8192 f32 accumulators
#define FLAG_OFS NACC      // int flag lives after the accumulators in ws

__device__ __forceinline__ float bf2f(unsigned short h) {
    unsigned u = ((unsigned)h) << 16;
    float f;
    __builtin_memcpy(&f, &u, 4);
    return f;
}

// load element i of an input tensor, honoring detected storage dtype
__device__ __forceinline__ float ldin(const void* p, int i, bool f32m) {
    if (f32m) return ((const float*)p)[i];
    return bf2f(((const unsigned short*)p)[i]);
}

// Zero the f32 accumulator; block 0 additionally sniffs sigmas' storage dtype.
// Genuine bf16 sigmas (0.1..0.6) have sign=0, exp in [123,126]. If the array is
// really f32, every odd short is low-order mantissa bits (~random) and fails.
__global__ void zero_detect(const unsigned short* __restrict__ sig, float* __restrict__ ws) {
    int i = blockIdx.x * blockDim.x + threadIdx.x;
    if (i < NACC) ws[i] = 0.0f;
    if (blockIdx.x == 0) {
        __shared__ int f;
        if (threadIdx.x == 0) f = 0;
        __syncthreads();
        unsigned short h = sig[threadIdx.x];  // first 256 shorts: in-bounds in both modes
        int sign = h >> 15;
        int e = (h >> 7) & 0xFF;
        if (sign != 0 || e < 123 || e > 126) atomicOr(&f, 1);
        __syncthreads();
        if (threadIdx.x == 0) ((int*)ws)[FLAG_OFS] = f;  // 1 => f32 storage
    }
}

__global__ __launch_bounds__(NPTS) void sparse_main(
    const void* __restrict__ x,
    const void* __restrict__ means,
    const void* __restrict__ sigmas,
    const void* __restrict__ values,
    const void* __restrict__ su,
    const void* __restrict__ ru,
    float* __restrict__ ws,
    const int* __restrict__ flag)
{
    const int k = blockIdx.x, b = blockIdx.y;
    const int tid = threadIdx.x;
    const bool f32m = (*flag != 0);

    __shared__ float m0s[CQ], m1s[CQ], i0s[CQ], i1s[CQ], valc[CQ];
    __shared__ int ids[NPTS];
    __shared__ float part[6][CQ];
    __shared__ float wnorm[CQ];

    const int gk = b * KQ + k;  // group index

    // per-gaussian data -> LDS
    if (tid < CQ) {
        int cb = gk * CQ + tid;
        m0s[tid] = ldin(means, cb * 2 + 0, f32m);
        m1s[tid] = ldin(means, cb * 2 + 1, f32m);
        float s0 = ldin(sigmas, cb * 2 + 0, f32m);
        float s1 = ldin(sigmas, cb * 2 + 1, f32m);
        i0s[tid] = __fsqrt_rn(__fdiv_rn(1.0f, __fadd_rn(1e-6f, s0)));
        i1s[tid] = __fsqrt_rn(__fdiv_rn(1.0f, __fadd_rn(1e-6f, s1)));
        valc[tid] = ldin(values, cb, f32m);
    }

    // ---- generate this thread's point (point tid = c*12 + j) ----
    const int c = tid / 12, j = tid % 12;
    const int cb = gk * CQ + c;
    const float mm0 = ldin(means, cb * 2 + 0, f32m);
    const float mm1 = ldin(means, cb * 2 + 1, f32m);
    const float CEPS = (float)(1.0 - 1e-6);  // f32(0.999999)

    int p0, p1;
    if (j < 4) {
        // fm order: (T,T),(T,F),(F,T),(F,F); True->floor, False->ceil
        p0 = (int)((j >= 2) ? ceilf(mm0) : floorf(mm0));
        p1 = (int)((j & 1) ? ceilf(mm1) : floorf(mm1));
    } else if (j < 8) {
        int ub = (cb * 4 + (j - 4)) * 2;
        float u0 = ldin(su, ub, f32m), u1 = ldin(su, ub + 1, f32m);
        // floor((u*(1-eps))*rng), pure f32 RN, no fma contraction
        p0 = (int)floorf(__fmul_rn(__fmul_rn(u0, CEPS), 1024.0f));
        p1 = (int)floorf(__fmul_rn(__fmul_rn(u1, CEPS), 1024.0f));
    } else {
        int ub = (cb * 4 + (j - 8)) * 2;
        float u0 = ldin(ru, ub, f32m), u1 = ldin(ru, ub + 1, f32m);
        float mn0 = rintf(mm0), mn1 = rintf(mm1);  // jnp.round = half-even
        float lo0 = mn0 - 8.0f; if (lo0 < 0.0f) lo0 = 0.0f; if (mn0 + 8.0f > 1024.0f) lo0 = 1008.0f;
        float lo1 = mn1 - 8.0f; if (lo1 < 0.0f) lo1 = 0.0f; if (mn1 + 8.0f > 1024.0f) lo1 = 1008.0f;
        p0 = (int)floorf(__fadd_rn(__fmul_rn(__fmul_rn(u0, CEPS), 16.0f), lo0));
        p1 = (int)floorf(__fadd_rn(__fmul_rn(__fmul_rn(u1, CEPS), 16.0f), lo1));
    }
    ids[tid] = p0 * 1024 + p1;
    __syncthreads();

    // ---- dup mark: first occurrence (lowest point index) kept ----
    bool dup = false;
    {
        const int myid = ids[tid];
        for (int t = 0; t < tid; ++t) dup = dup || (ids[t] == myid);
    }

    // ---- densities vs all 32 gaussians (dups zeroed pre-normalization) ----
    const float pf0 = (float)p0, pf1 = (float)p1;
    float pr[CQ];
    #pragma unroll
    for (int cc = 0; cc < CQ; ++cc) {
        float d0 = (pf0 - m0s[cc]) * i0s[cc];
        float d1 = (pf1 - m1s[cc]) * i1s[cc];
        float e = __expf(-0.5f * (d0 * d0 + d1 * d1));
        pr[cc] = dup ? 0.0f : e;
    }

    // ---- per-gaussian sums over 384 points: wave butterfly + cross-wave ----
    const int lane = tid & 63, wid = tid >> 6;
    #pragma unroll
    for (int cc = 0; cc < CQ; ++cc) {
        float v = pr[cc];
        #pragma unroll
        for (int off = 32; off > 0; off >>= 1) v += __shfl_xor(v, off, 64);
        if (lane == 0) part[wid][cc] = v;
    }
    __syncthreads();
    if (tid < CQ) {
        float s = 0.0f;
        #pragma unroll
        for (int w = 0; w < 6; ++w) s += part[w][tid];
        wnorm[tid] = valc[tid] / s;  // value_c / S_c  (S_c > 0: own corners survive)
    }
    __syncthreads();

    // ---- vals + scatter ----
    if (!dup) {
        float vals = 0.0f;
        #pragma unroll
        for (int cc = 0; cc < CQ; ++cc) vals += pr[cc] * wnorm[cc];
        int g1 = p1 < 0 ? 0 : (p1 > OUTN - 1 ? OUTN - 1 : p1);  // jnp gather clamps
        float contrib = vals * ldin(x, b * OUTN + g1, f32m);
        if (p0 >= 0 && p0 < OUTN)  // jnp scatter drops OOB
            atomicAdd(&ws[b * OUTN + p0], contrib);
    }
}

__global__ void cast_out(const float* __restrict__ ws, void* __restrict__ out,
                         const int* __restrict__ flag) {
    int i = blockIdx.x * blockDim.x + threadIdx.x;
    if (i < NACC) {
        float f = ws[i];
        if (*flag != 0) {
            ((float*)out)[i] = f;
        } else {
            unsigned u; __builtin_memcpy(&u, &f, 4);
            unsigned r = (u + 0x7FFFu + ((u >> 16) & 1u)) >> 16;  // RNE f32->bf16
            ((unsigned short*)out)[i] = (unsigned short)r;
        }
    }
}

extern "C" void kernel_launch(void* const* d_in, const int* in_sizes, int n_in,
                              void* d_out, int out_size, void* d_ws, size_t ws_size,
                              hipStream_t stream) {
    float* ws = (float*)d_ws;
    const int* flag = ((const int*)d_ws) + FLAG_OFS;

    zero_detect<<<dim3((NACC + 255) / 256), dim3(256), 0, stream>>>(
        (const unsigned short*)d_in[2], ws);
    sparse_main<<<dim3(KQ, BQ), dim3(NPTS), 0, stream>>>(
        d_in[0], d_in[1], d_in[2], d_in[3], d_in[4], d_in[5], ws, flag);
    cast_out<<<dim3((NACC + 255) / 256), dim3(256), 0, stream>>>(ws, d_out, flag);
}

// Round 3
// 126.740 us; speedup vs baseline: 1.6301x; 1.6301x over previous
//
#include <hip/hip_runtime.h>

#define CQ 32
#define KQ 128
#define NPTS 384
#define OUTN 1024
#define BQ 8
#define NACC (BQ * OUTN)
#define HSZ 1024   // LDS hash slots (384 keys -> load factor 0.375)

__global__ void zero_out(float* __restrict__ out) {
    int i = blockIdx.x * blockDim.x + threadIdx.x;
    if (i < NACC) out[i] = 0.0f;
}

__global__ __launch_bounds__(NPTS) void sparse_main(
    const float* __restrict__ x,
    const float* __restrict__ means,
    const float* __restrict__ sigmas,
    const float* __restrict__ values,
    const float* __restrict__ su,
    const float* __restrict__ ru,
    float* __restrict__ out)
{
    const int k = blockIdx.x, b = blockIdx.y;
    const int tid = threadIdx.x;

    __shared__ float m0s[CQ], m1s[CQ], i0s[CQ], i1s[CQ], valc[CQ];
    __shared__ int htab[HSZ];
    __shared__ float part[6][CQ];
    __shared__ float wnorm[CQ];

    const int gk = b * KQ + k;

    // init hash table + stage per-gaussian params in LDS
    for (int i = tid; i < HSZ; i += NPTS) htab[i] = -1;
    if (tid < CQ) {
        int cb = gk * CQ + tid;
        m0s[tid] = means[cb * 2 + 0];
        m1s[tid] = means[cb * 2 + 1];
        i0s[tid] = __fsqrt_rn(__fdiv_rn(1.0f, __fadd_rn(1e-6f, sigmas[cb * 2 + 0])));
        i1s[tid] = __fsqrt_rn(__fdiv_rn(1.0f, __fadd_rn(1e-6f, sigmas[cb * 2 + 1])));
        valc[tid] = values[cb];
    }
    __syncthreads();

    // ---- generate this thread's point (point tid = c*12 + j) ----
    const int c = tid / 12, j = tid % 12;
    const int cb = gk * CQ + c;
    const float mm0 = m0s[c], mm1 = m1s[c];
    const float CEPS = (float)(1.0 - 1e-6);  // exact f32 of the reference constant

    int p0, p1;
    if (j < 4) {
        // fm order: (T,T),(T,F),(F,T),(F,F); True->floor, False->ceil
        p0 = (int)((j >= 2) ? ceilf(mm0) : floorf(mm0));
        p1 = (int)((j & 1) ? ceilf(mm1) : floorf(mm1));
    } else if (j < 8) {
        int ub = (cb * 4 + (j - 4)) * 2;
        float u0 = su[ub], u1 = su[ub + 1];
        // floor((u*(1-eps))*rng), pure f32 RN, no fma contraction
        p0 = (int)floorf(__fmul_rn(__fmul_rn(u0, CEPS), 1024.0f));
        p1 = (int)floorf(__fmul_rn(__fmul_rn(u1, CEPS), 1024.0f));
    } else {
        int ub = (cb * 4 + (j - 8)) * 2;
        float u0 = ru[ub], u1 = ru[ub + 1];
        float mn0 = rintf(mm0), mn1 = rintf(mm1);  // jnp.round = half-even
        float lo0 = mn0 - 8.0f; if (lo0 < 0.0f) lo0 = 0.0f; if (mn0 + 8.0f > 1024.0f) lo0 = 1008.0f;
        float lo1 = mn1 - 8.0f; if (lo1 < 0.0f) lo1 = 0.0f; if (mn1 + 8.0f > 1024.0f) lo1 = 1008.0f;
        p0 = (int)floorf(__fadd_rn(__fmul_rn(__fmul_rn(u0, CEPS), 16.0f), lo0));
        p1 = (int)floorf(__fadd_rn(__fmul_rn(__fmul_rn(u1, CEPS), 16.0f), lo1));
    }

    // ---- dedup via LDS hash (any single survivor per id is numerically
    // identical to the reference's stable-sort choice: equal id => equal
    // coords => equal density row => equal vals and scatter target) ----
    const int myid = p0 * 1024 + p1;           // in [0, 1048575], -1 is safe sentinel
    int slot = (int)(((unsigned)myid * 2654435761u) >> 22);
    bool dup = false;
    while (true) {
        int prev = atomicCAS(&htab[slot], -1, myid);
        if (prev == -1) break;                 // claimed: survivor
        if (prev == myid) { dup = true; break; }
        slot = (slot + 1) & (HSZ - 1);
    }

    // ---- densities vs all 32 gaussians (dups zeroed pre-normalization) ----
    const float pf0 = (float)p0, pf1 = (float)p1;
    float pr[CQ];
    #pragma unroll
    for (int cc = 0; cc < CQ; ++cc) {
        float d0 = (pf0 - m0s[cc]) * i0s[cc];
        float d1 = (pf1 - m1s[cc]) * i1s[cc];
        float e = __expf(-0.5f * (d0 * d0 + d1 * d1));
        pr[cc] = dup ? 0.0f : e;
    }

    // ---- per-gaussian sums over 384 points: wave butterfly + cross-wave ----
    const int lane = tid & 63, wid = tid >> 6;
    #pragma unroll
    for (int cc = 0; cc < CQ; ++cc) {
        float v = pr[cc];
        #pragma unroll
        for (int off = 32; off > 0; off >>= 1) v += __shfl_xor(v, off, 64);
        if (lane == 0) part[wid][cc] = v;
    }
    __syncthreads();
    if (tid < CQ) {
        float s = 0.0f;
        #pragma unroll
        for (int w = 0; w < 6; ++w) s += part[w][tid];
        wnorm[tid] = valc[tid] / s;  // value_c / S_c (S_c > 0: own corners survive)
    }
    __syncthreads();

    // ---- vals + scatter straight into the f32 output ----
    if (!dup) {
        float vals = 0.0f;
        #pragma unroll
        for (int cc = 0; cc < CQ; ++cc) vals += pr[cc] * wnorm[cc];
        int g1 = p1 < 0 ? 0 : (p1 > OUTN - 1 ? OUTN - 1 : p1);  // jnp gather clamps
        float contrib = vals * x[b * OUTN + g1];
        if (p0 >= 0 && p0 < OUTN)  // jnp scatter drops OOB
            atomicAdd(&out[b * OUTN + p0], contrib);
    }
}

extern "C" void kernel_launch(void* const* d_in, const int* in_sizes, int n_in,
                              void* d_out, int out_size, void* d_ws, size_t ws_size,
                              hipStream_t stream) {
    const float* x      = (const float*)d_in[0];
    const float* means  = (const float*)d_in[1];
    const float* sigmas = (const float*)d_in[2];
    const float* values = (const float*)d_in[3];
    const float* su     = (const float*)d_in[4];
    const float* ru     = (const float*)d_in[5];
    float* out = (float*)d_out;

    zero_out<<<dim3((NACC + 255) / 256), dim3(256), 0, stream>>>(out);
    sparse_main<<<dim3(KQ, BQ), dim3(NPTS), 0, stream>>>(x, means, sigmas, values, su, ru, out);
}

// Round 4
// 117.346 us; speedup vs baseline: 1.7606x; 1.0800x over previous
//
#include <hip/hip_runtime.h>

#define CQ 32
#define KQ 128
#define NPTS 384
#define OUTN 1024
#define BQ 8
#define NACC (BQ * OUTN)
#define HSZ 1024
#define NBLK (BQ * KQ)
#define WS_NEED ((size_t)NBLK * OUTN * sizeof(float))

__global__ void zero_out(float* __restrict__ out) {
    int i = blockIdx.x * blockDim.x + threadIdx.x;
    if (i < NACC) out[i] = 0.0f;
}

// use_ws==1: accumulate in LDS, write private 4KB partial to dst=ws (no global atomics)
// use_ws==0: legacy path, atomicAdd directly into dst=out (requires pre-zeroed out)
__global__ __launch_bounds__(NPTS) void sparse_part(
    const float* __restrict__ x,
    const float* __restrict__ means,
    const float* __restrict__ sigmas,
    const float* __restrict__ values,
    const float* __restrict__ su,
    const float* __restrict__ ru,
    float* __restrict__ dst,
    int use_ws)
{
    const int k = blockIdx.x, b = blockIdx.y;
    const int tid = threadIdx.x;

    __shared__ float m0s[CQ], m1s[CQ], i0s[CQ], i1s[CQ], valc[CQ];
    __shared__ int htab[HSZ];
    __shared__ float part[6][CQ];
    __shared__ float wnorm[CQ];
    __shared__ float acc[OUTN];

    const int gk = b * KQ + k;

    for (int i = tid; i < HSZ; i += NPTS) htab[i] = -1;
    if (use_ws) {
        for (int i = tid; i < OUTN; i += NPTS) acc[i] = 0.0f;
    }
    if (tid < CQ) {
        int cb = gk * CQ + tid;
        m0s[tid] = means[cb * 2 + 0];
        m1s[tid] = means[cb * 2 + 1];
        i0s[tid] = __fsqrt_rn(__fdiv_rn(1.0f, __fadd_rn(1e-6f, sigmas[cb * 2 + 0])));
        i1s[tid] = __fsqrt_rn(__fdiv_rn(1.0f, __fadd_rn(1e-6f, sigmas[cb * 2 + 1])));
        valc[tid] = values[cb];
    }
    __syncthreads();

    // ---- generate this thread's point (point tid = c*12 + j) ----
    const int c = tid / 12, j = tid % 12;
    const int cb = gk * CQ + c;
    const float mm0 = m0s[c], mm1 = m1s[c];
    const float CEPS = (float)(1.0 - 1e-6);  // exact f32 of the reference constant

    int p0, p1;
    if (j < 4) {
        // fm order: (T,T),(T,F),(F,T),(F,F); True->floor, False->ceil
        p0 = (int)((j >= 2) ? ceilf(mm0) : floorf(mm0));
        p1 = (int)((j & 1) ? ceilf(mm1) : floorf(mm1));
    } else if (j < 8) {
        int ub = (cb * 4 + (j - 4)) * 2;
        float u0 = su[ub], u1 = su[ub + 1];
        // floor((u*(1-eps))*rng), pure f32 RN, no fma contraction
        p0 = (int)floorf(__fmul_rn(__fmul_rn(u0, CEPS), 1024.0f));
        p1 = (int)floorf(__fmul_rn(__fmul_rn(u1, CEPS), 1024.0f));
    } else {
        int ub = (cb * 4 + (j - 8)) * 2;
        float u0 = ru[ub], u1 = ru[ub + 1];
        float mn0 = rintf(mm0), mn1 = rintf(mm1);  // jnp.round = half-even
        float lo0 = mn0 - 8.0f; if (lo0 < 0.0f) lo0 = 0.0f; if (mn0 + 8.0f > 1024.0f) lo0 = 1008.0f;
        float lo1 = mn1 - 8.0f; if (lo1 < 0.0f) lo1 = 0.0f; if (mn1 + 8.0f > 1024.0f) lo1 = 1008.0f;
        p0 = (int)floorf(__fadd_rn(__fmul_rn(__fmul_rn(u0, CEPS), 16.0f), lo0));
        p1 = (int)floorf(__fadd_rn(__fmul_rn(__fmul_rn(u1, CEPS), 16.0f), lo1));
    }

    // ---- dedup via LDS hash (any survivor per id is numerically identical
    // to the reference's stable-sort choice: equal id => equal coords =>
    // equal density row => equal vals and scatter target) ----
    const int myid = p0 * 1024 + p1;
    int slot = (int)(((unsigned)myid * 2654435761u) >> 22);
    bool dup = false;
    while (true) {
        int prev = atomicCAS(&htab[slot], -1, myid);
        if (prev == -1) break;
        if (prev == myid) { dup = true; break; }
        slot = (slot + 1) & (HSZ - 1);
    }

    // ---- densities vs all 32 gaussians (dups zeroed pre-normalization) ----
    const float pf0 = (float)p0, pf1 = (float)p1;
    float pr[CQ];
    #pragma unroll
    for (int cc = 0; cc < CQ; ++cc) {
        float d0 = (pf0 - m0s[cc]) * i0s[cc];
        float d1 = (pf1 - m1s[cc]) * i1s[cc];
        float e = __expf(-0.5f * (d0 * d0 + d1 * d1));
        pr[cc] = dup ? 0.0f : e;
    }

    // ---- per-gaussian sums over 384 points: wave butterfly + cross-wave ----
    const int lane = tid & 63, wid = tid >> 6;
    #pragma unroll
    for (int cc = 0; cc < CQ; ++cc) {
        float v = pr[cc];
        #pragma unroll
        for (int off = 32; off > 0; off >>= 1) v += __shfl_xor(v, off, 64);
        if (lane == 0) part[wid][cc] = v;
    }
    __syncthreads();
    if (tid < CQ) {
        float s = 0.0f;
        #pragma unroll
        for (int w = 0; w < 6; ++w) s += part[w][tid];
        wnorm[tid] = valc[tid] / s;  // value_c / S_c (S_c > 0: own corners survive)
    }
    __syncthreads();

    // ---- vals + scatter ----
    if (!dup) {
        float vals = 0.0f;
        #pragma unroll
        for (int cc = 0; cc < CQ; ++cc) vals += pr[cc] * wnorm[cc];
        int g1 = p1 < 0 ? 0 : (p1 > OUTN - 1 ? OUTN - 1 : p1);  // jnp gather clamps
        float contrib = vals * x[b * OUTN + g1];
        if (p0 >= 0 && p0 < OUTN) {                              // jnp scatter drops OOB
            if (use_ws) atomicAdd(&acc[p0], contrib);            // LDS atomic (ds_add)
            else        atomicAdd(&dst[b * OUTN + p0], contrib); // legacy global atomic
        }
    }

    if (use_ws) {
        __syncthreads();
        float* w = dst + (size_t)gk * OUTN;
        for (int i = tid; i < OUTN; i += NPTS) w[i] = acc[i];    // coalesced stream-out
    }
}

// out[b][c] = sum_k ws[(b*KQ+k)*OUTN + c]; 8192 threads, coalesced strided reads
__global__ void reduce_ws(const float* __restrict__ ws, float* __restrict__ out) {
    int t = blockIdx.x * blockDim.x + threadIdx.x;
    if (t >= NACC) return;
    int b = t >> 10, cidx = t & (OUTN - 1);
    const float* p = ws + (size_t)b * KQ * OUTN + cidx;
    float s0 = 0.0f, s1 = 0.0f, s2 = 0.0f, s3 = 0.0f;
    #pragma unroll
    for (int k = 0; k < KQ; k += 4) {
        s0 += p[(size_t)(k + 0) * OUTN];
        s1 += p[(size_t)(k + 1) * OUTN];
        s2 += p[(size_t)(k + 2) * OUTN];
        s3 += p[(size_t)(k + 3) * OUTN];
    }
    out[t] = (s0 + s1) + (s2 + s3);
}

extern "C" void kernel_launch(void* const* d_in, const int* in_sizes, int n_in,
                              void* d_out, int out_size, void* d_ws, size_t ws_size,
                              hipStream_t stream) {
    const float* x      = (const float*)d_in[0];
    const float* means  = (const float*)d_in[1];
    const float* sigmas = (const float*)d_in[2];
    const float* values = (const float*)d_in[3];
    const float* su     = (const float*)d_in[4];
    const float* ru     = (const float*)d_in[5];
    float* out = (float*)d_out;
    float* ws  = (float*)d_ws;

    if (ws_size >= WS_NEED) {
        sparse_part<<<dim3(KQ, BQ), dim3(NPTS), 0, stream>>>(
            x, means, sigmas, values, su, ru, ws, 1);
        reduce_ws<<<dim3((NACC + 127) / 128), dim3(128), 0, stream>>>(ws, out);
    } else {
        zero_out<<<dim3((NACC + 255) / 256), dim3(256), 0, stream>>>(out);
        sparse_part<<<dim3(KQ, BQ), dim3(NPTS), 0, stream>>>(
            x, means, sigmas, values, su, ru, out, 0);
    }
}

// Round 5
// 91.861 us; speedup vs baseline: 2.2491x; 1.2774x over previous
//
#include <hip/hip_runtime.h>

#define CQ 32
#define KQ 128
#define NPTS 384
#define OUTN 1024
#define BQ 8
#define NACC (BQ * OUTN)
#define HSZ 1024
#define GPB 2                      // k-groups per block
#define KB (KQ / GPB)              // 64 block columns
#define WS_NEED ((size_t)BQ * KB * OUTN * sizeof(float))

__global__ void zero_out(float* __restrict__ out) {
    int i = blockIdx.x * blockDim.x + threadIdx.x;
    if (i < NACC) out[i] = 0.0f;
}

// wave64 sum via DPP; result valid in lane 63 (invalid-source lanes read 0).
__device__ __forceinline__ float wave_red_dpp(float v) {
#define DPPADD(ctrl)                                                              \
    {                                                                             \
        int t_ = __builtin_amdgcn_update_dpp(0, __float_as_int(v), (ctrl), 0xF,   \
                                             0xF, true);                          \
        v += __int_as_float(t_);                                                  \
    }
    DPPADD(0x111)  // row_shr:1
    DPPADD(0x112)  // row_shr:2
    DPPADD(0x114)  // row_shr:4
    DPPADD(0x118)  // row_shr:8   -> lane 15 of each row16 = row sum
    DPPADD(0x142)  // row_bcast:15 -> lane31 = rows0-1, lane63 = rows2-3
    DPPADD(0x143)  // row_bcast:31 -> lane63 = wave sum
#undef DPPADD
    return v;
}

// use_ws==1: LDS-accumulate GPB groups, stream 4KB partial to dst=ws
// use_ws==0: fallback, global atomicAdd into dst=out (pre-zeroed)
__global__ __launch_bounds__(NPTS) void sparse_part(
    const float* __restrict__ x,
    const float* __restrict__ means,
    const float* __restrict__ sigmas,
    const float* __restrict__ values,
    const float* __restrict__ su,
    const float* __restrict__ ru,
    float* __restrict__ dst,
    int use_ws)
{
    const int kb = blockIdx.x, b = blockIdx.y;
    const int tid = threadIdx.x;
    const int lane = tid & 63, wid = tid >> 6;

    __shared__ float m0s[CQ], m1s[CQ], i0s[CQ], i1s[CQ], valc[CQ];
    __shared__ int htab[HSZ];
    __shared__ float part[6][CQ];
    __shared__ float wnorm[CQ];
    __shared__ float acc[OUTN];

    if (use_ws) {
        for (int i = tid; i < OUTN; i += NPTS) acc[i] = 0.0f;
    }

    const int c = tid / 12, j = tid % 12;   // point tid = c*12 + j
    const float CEPS = (float)(1.0 - 1e-6); // exact f32 of reference constant

    for (int g = 0; g < GPB; ++g) {
        const int k = kb * GPB + g;
        const int gk = b * KQ + k;

        // ---- stage group params + reset hash ----
        for (int i = tid; i < HSZ; i += NPTS) htab[i] = -1;
        if (tid < CQ) {
            int cb = gk * CQ + tid;
            m0s[tid] = means[cb * 2 + 0];
            m1s[tid] = means[cb * 2 + 1];
            i0s[tid] = __fsqrt_rn(__fdiv_rn(1.0f, __fadd_rn(1e-6f, sigmas[cb * 2 + 0])));
            i1s[tid] = __fsqrt_rn(__fdiv_rn(1.0f, __fadd_rn(1e-6f, sigmas[cb * 2 + 1])));
            valc[tid] = values[cb];
        }
        __syncthreads();

        // ---- generate this thread's point ----
        const int cb = gk * CQ + c;
        const float mm0 = m0s[c], mm1 = m1s[c];
        int p0, p1;
        if (j < 4) {
            // fm order: (T,T),(T,F),(F,T),(F,F); True->floor, False->ceil
            p0 = (int)((j >= 2) ? ceilf(mm0) : floorf(mm0));
            p1 = (int)((j & 1) ? ceilf(mm1) : floorf(mm1));
        } else if (j < 8) {
            int ub = (cb * 4 + (j - 4)) * 2;
            float u0 = su[ub], u1 = su[ub + 1];
            // floor((u*(1-eps))*rng), pure f32 RN, no fma contraction
            p0 = (int)floorf(__fmul_rn(__fmul_rn(u0, CEPS), 1024.0f));
            p1 = (int)floorf(__fmul_rn(__fmul_rn(u1, CEPS), 1024.0f));
        } else {
            int ub = (cb * 4 + (j - 8)) * 2;
            float u0 = ru[ub], u1 = ru[ub + 1];
            float mn0 = rintf(mm0), mn1 = rintf(mm1);  // jnp.round = half-even
            float lo0 = mn0 - 8.0f; if (lo0 < 0.0f) lo0 = 0.0f; if (mn0 + 8.0f > 1024.0f) lo0 = 1008.0f;
            float lo1 = mn1 - 8.0f; if (lo1 < 0.0f) lo1 = 0.0f; if (mn1 + 8.0f > 1024.0f) lo1 = 1008.0f;
            p0 = (int)floorf(__fadd_rn(__fmul_rn(__fmul_rn(u0, CEPS), 16.0f), lo0));
            p1 = (int)floorf(__fadd_rn(__fmul_rn(__fmul_rn(u1, CEPS), 16.0f), lo1));
        }

        // ---- dedup via LDS hash (any survivor per id is numerically identical
        // to the reference's stable-sort pick: equal id => equal coords =>
        // equal density row => equal vals and scatter target) ----
        const int myid = p0 * 1024 + p1;
        int slot = (int)(((unsigned)myid * 2654435761u) >> 22);
        bool dup = false;
        while (true) {
            int prev = atomicCAS(&htab[slot], -1, myid);
            if (prev == -1) break;
            if (prev == myid) { dup = true; break; }
            slot = (slot + 1) & (HSZ - 1);
        }

        // ---- densities vs all 32 gaussians (dups zeroed pre-normalization) ----
        const float pf0 = (float)p0, pf1 = (float)p1;
        float pr[CQ];
        #pragma unroll
        for (int cc = 0; cc < CQ; ++cc) {
            float d0 = (pf0 - m0s[cc]) * i0s[cc];
            float d1 = (pf1 - m1s[cc]) * i1s[cc];
            float e = __expf(-0.5f * (d0 * d0 + d1 * d1));
            pr[cc] = dup ? 0.0f : e;
        }

        // ---- per-gaussian sums over 384 points: DPP wave sum + cross-wave ----
        #pragma unroll
        for (int cc = 0; cc < CQ; ++cc) {
            float v = wave_red_dpp(pr[cc]);
            if (lane == 63) part[wid][cc] = v;
        }
        __syncthreads();
        if (tid < CQ) {
            float s = 0.0f;
            #pragma unroll
            for (int w = 0; w < 6; ++w) s += part[w][tid];
            wnorm[tid] = valc[tid] / s;  // value_c / S_c (S_c > 0: own corners survive)
        }
        __syncthreads();

        // ---- vals + scatter ----
        if (!dup) {
            float vals = 0.0f;
            #pragma unroll
            for (int cc = 0; cc < CQ; ++cc) vals += pr[cc] * wnorm[cc];
            int g1 = p1 < 0 ? 0 : (p1 > OUTN - 1 ? OUTN - 1 : p1);  // jnp gather clamps
            float contrib = vals * x[b * OUTN + g1];
            if (p0 >= 0 && p0 < OUTN) {                              // jnp scatter drops OOB
                if (use_ws) atomicAdd(&acc[p0], contrib);            // LDS ds_add
                else        atomicAdd(&dst[b * OUTN + p0], contrib); // fallback
            }
        }
        __syncthreads();  // all hash probes/acc adds done before next group reuses LDS
    }

    if (use_ws) {
        float* w = dst + ((size_t)b * KB + kb) * OUTN;
        for (int i = tid; i < OUTN; i += NPTS) w[i] = acc[i];  // coalesced stream-out
    }
}

// out[b][c] = sum over 64 partials; 8192 threads, coalesced strided reads
__global__ void reduce_ws(const float* __restrict__ ws, float* __restrict__ out) {
    int t = blockIdx.x * blockDim.x + threadIdx.x;
    if (t >= NACC) return;
    int b = t >> 10, cidx = t & (OUTN - 1);
    const float* p = ws + (size_t)b * KB * OUTN + cidx;
    float s0 = 0.0f, s1 = 0.0f, s2 = 0.0f, s3 = 0.0f;
    #pragma unroll
    for (int k = 0; k < KB; k += 4) {
        s0 += p[(size_t)(k + 0) * OUTN];
        s1 += p[(size_t)(k + 1) * OUTN];
        s2 += p[(size_t)(k + 2) * OUTN];
        s3 += p[(size_t)(k + 3) * OUTN];
    }
    out[t] = (s0 + s1) + (s2 + s3);
}

extern "C" void kernel_launch(void* const* d_in, const int* in_sizes, int n_in,
                              void* d_out, int out_size, void* d_ws, size_t ws_size,
                              hipStream_t stream) {
    const float* x      = (const float*)d_in[0];
    const float* means  = (const float*)d_in[1];
    const float* sigmas = (const float*)d_in[2];
    const float* values = (const float*)d_in[3];
    const float* su     = (const float*)d_in[4];
    const float* ru     = (const float*)d_in[5];
    float* out = (float*)d_out;
    float* ws  = (float*)d_ws;

    if (ws_size >= WS_NEED) {
        sparse_part<<<dim3(KB, BQ), dim3(NPTS), 0, stream>>>(
            x, means, sigmas, values, su, ru, ws, 1);
        reduce_ws<<<dim3((NACC + 127) / 128), dim3(128), 0, stream>>>(ws, out);
    } else {
        zero_out<<<dim3((NACC + 255) / 256), dim3(256), 0, stream>>>(out);
        sparse_part<<<dim3(KB, BQ), dim3(NPTS), 0, stream>>>(
            x, means, sigmas, values, su, ru, out, 0);
    }
}